// Round 1
// baseline (141.175 us; speedup 1.0000x reference)
//
#include <hip/hip_runtime.h>
#include <hip/hip_bf16.h>

#define NB 4096
#define ND 512

typedef short bf16x8 __attribute__((ext_vector_type(8)));
typedef float f32x4 __attribute__((ext_vector_type(4)));

__device__ __forceinline__ float bf2f(unsigned short u) {
    return __uint_as_float(((unsigned int)u) << 16);
}

__device__ __forceinline__ unsigned short f2bf(float f) {
    unsigned int u = __float_as_uint(f);
    unsigned int r = (u + 0x7FFFu + ((u >> 16) & 1u)) >> 16;
    return (unsigned short)r;
}

// ---------------- normalize + cast to bf16 ----------------
// grid (4096, 3), block 128. Each block: one row of one latent.
__global__ __launch_bounds__(128) void nrm_kernel(
    const float* __restrict__ z0, const float* __restrict__ z1,
    const float* __restrict__ z2, unsigned short* __restrict__ nrm)
{
    const int row = blockIdx.x;
    const int p = blockIdx.y;
    const float* z = (p == 0) ? z0 : (p == 1) ? z1 : z2;
    const float4 v = reinterpret_cast<const float4*>(z)[row * (ND / 4) + threadIdx.x];
    float ss = v.x * v.x + v.y * v.y + v.z * v.z + v.w * v.w;
    #pragma unroll
    for (int m = 32; m >= 1; m >>= 1) ss += __shfl_xor(ss, m);
    __shared__ float sred[2];
    if ((threadIdx.x & 63) == 0) sred[threadIdx.x >> 6] = ss;
    __syncthreads();
    const float inv = 1.0f / fmaxf(sqrtf(sred[0] + sred[1]), 1e-8f);
    ushort4 o;
    o.x = f2bf(v.x * inv);
    o.y = f2bf(v.y * inv);
    o.z = f2bf(v.z * inv);
    o.w = f2bf(v.w * inv);
    unsigned short* dst = nrm + ((size_t)p * NB + row) * ND + threadIdx.x * 4;
    *reinterpret_cast<ushort4*>(dst) = o;
}

// ---------------- diag: sim_ii = dot(Ni[i], Nj[i]) ----------------
// one wave per (pair, row); 3*4096 waves -> 3072 blocks of 256
__global__ __launch_bounds__(256) void diag_kernel(
    const unsigned short* __restrict__ nrm, float* __restrict__ diag)
{
    const int gw = (blockIdx.x * 256 + threadIdx.x) >> 6;
    const int lane = threadIdx.x & 63;
    const int p = gw >> 12;
    const int row = gw & (NB - 1);
    const int ia = (p == 2) ? 1 : 0;
    const int ib = (p == 0) ? 1 : 2;
    const unsigned short* a = nrm + ((size_t)ia * NB + row) * ND + lane * 8;
    const unsigned short* b = nrm + ((size_t)ib * NB + row) * ND + lane * 8;
    bf16x8 av = *(const bf16x8*)a;
    bf16x8 bv = *(const bf16x8*)b;
    float d = 0.f;
    #pragma unroll
    for (int j = 0; j < 8; ++j)
        d += bf2f((unsigned short)av[j]) * bf2f((unsigned short)bv[j]);
    #pragma unroll
    for (int m = 32; m >= 1; m >>= 1) d += __shfl_xor(d, m);
    if (lane == 0) diag[gw] = d;
}

// ---------------- fused pair GEMM + exp + row/col partial sums ----------------
// grid (32, 32, 3), block 256 (4 waves, 2x2 wave grid, 64x64 per wave)
__global__ __launch_bounds__(256) void pair_gemm_kernel(
    const unsigned short* __restrict__ nrm,
    float* __restrict__ rowsum, float* __restrict__ colsum)
{
    constexpr int BM = 128, BK = 64;
    const int p = blockIdx.z;
    const int ia = (p == 2) ? 1 : 0;
    const int ib = (p == 0) ? 1 : 2;

    const char* Abase = (const char*)(nrm + (size_t)ia * NB * ND) + (size_t)blockIdx.y * BM * (ND * 2);
    const char* Bbase = (const char*)(nrm + (size_t)ib * NB * ND) + (size_t)blockIdx.x * BM * (ND * 2);

    __shared__ alignas(16) unsigned short sA[BM * BK];
    __shared__ alignas(16) unsigned short sB[BM * BK];

    const int tid = threadIdx.x;
    const int lane = tid & 63;
    const int w = tid >> 6;
    const int wr = w >> 1, wc = w & 1;
    const int lr = lane & 15, lg = lane >> 4;

    f32x4 acc[4][4] = {};

    // Staging: 1024 chunks of 16B per tile. chunk c -> LDS byte c*16 (linear, as
    // global_load_lds requires). Source is INVERSE-swizzled: chunk col ^= (row&7),
    // so swizzled reads below see conflict-free layout (guide rule 21 / T2).
    int soff[4];
    #pragma unroll
    for (int it = 0; it < 4; ++it) {
        int c = (it * 4 + w) * 64 + lane;
        int r = c >> 3;                    // row within tile (8 chunks of 16B per row)
        int q = (c & 7) ^ (r & 7);         // swizzled 16B-chunk within the 128B row slice
        soff[it] = r * (ND * 2) + q * 16;  // global byte offset (row stride = 1024B)
    }

    for (int ks = 0; ks < ND / BK; ++ks) {
        const int kbyte = ks * BK * 2;
        #pragma unroll
        for (int it = 0; it < 4; ++it) {
            const char* gA = Abase + soff[it] + kbyte;
            const char* gB = Bbase + soff[it] + kbyte;
            char* lA = (char*)sA + (it * 4 + w) * 1024;
            char* lB = (char*)sB + (it * 4 + w) * 1024;
            __builtin_amdgcn_global_load_lds((const __attribute__((address_space(1))) void*)gA,
                                             (__attribute__((address_space(3))) void*)lA, 16, 0, 0);
            __builtin_amdgcn_global_load_lds((const __attribute__((address_space(1))) void*)gB,
                                             (__attribute__((address_space(3))) void*)lB, 16, 0, 0);
        }
        __syncthreads();
        #pragma unroll
        for (int kk = 0; kk < 2; ++kk) {
            bf16x8 af[4], bf[4];
            const int cb = kk * 64 + lg * 16;  // byte col of this lane's 8 K-elems
            #pragma unroll
            for (int m = 0; m < 4; ++m) {
                int r = wr * 64 + m * 16 + lr;
                af[m] = *(const bf16x8*)((const char*)sA + r * 128 + (cb ^ ((r & 7) << 4)));
            }
            #pragma unroll
            for (int n = 0; n < 4; ++n) {
                int r = wc * 64 + n * 16 + lr;
                bf[n] = *(const bf16x8*)((const char*)sB + r * 128 + (cb ^ ((r & 7) << 4)));
            }
            #pragma unroll
            for (int m = 0; m < 4; ++m)
                #pragma unroll
                for (int n = 0; n < 4; ++n)
                    acc[m][n] = __builtin_amdgcn_mfma_f32_16x16x32_bf16(af[m], bf[n], acc[m][n], 0, 0, 0);
        }
        __syncthreads();
    }

    // Epilogue: e = exp(10*sim - 10) = exp2(sim*10*log2e - 10*log2e); accumulate
    // per-row and per-col partials. C frag: col = lane&15, row = (lane>>4)*4 + reg.
    constexpr float C10 = 14.42695040888963f;
    float rs[4][4];
    float cs[4] = {0.f, 0.f, 0.f, 0.f};
    #pragma unroll
    for (int m = 0; m < 4; ++m)
        #pragma unroll
        for (int j = 0; j < 4; ++j) rs[m][j] = 0.f;

    #pragma unroll
    for (int m = 0; m < 4; ++m)
        #pragma unroll
        for (int n = 0; n < 4; ++n)
            #pragma unroll
            for (int j = 0; j < 4; ++j) {
                float e = exp2f(fmaf(acc[m][n][j], C10, -C10));
                rs[m][j] += e;
                cs[n] += e;
            }

    // row sums: reduce across the 16 lanes sharing lg (butterfly over lane&15 bits)
    #pragma unroll
    for (int m = 0; m < 4; ++m)
        #pragma unroll
        for (int j = 0; j < 4; ++j) {
            float v = rs[m][j];
            v += __shfl_xor(v, 1);
            v += __shfl_xor(v, 2);
            v += __shfl_xor(v, 4);
            v += __shfl_xor(v, 8);
            rs[m][j] = v;
        }
    // col sums: reduce across the 4 lane-groups (bits 16, 32)
    #pragma unroll
    for (int n = 0; n < 4; ++n) {
        float v = cs[n];
        v += __shfl_xor(v, 16);
        v += __shfl_xor(v, 32);
        cs[n] = v;
    }

    float* rowp = rowsum + p * NB + blockIdx.y * BM;
    float* colp = colsum + p * NB + blockIdx.x * BM;
    if (lr == 0) {
        #pragma unroll
        for (int m = 0; m < 4; ++m)
            #pragma unroll
            for (int j = 0; j < 4; ++j)
                atomicAdd(&rowp[wr * 64 + m * 16 + lg * 4 + j], rs[m][j]);
    }
    if (lg == 0) {
        #pragma unroll
        for (int n = 0; n < 4; ++n)
            atomicAdd(&colp[wc * 64 + n * 16 + lr], cs[n]);
    }
}

// ---------------- final reduce ----------------
__global__ __launch_bounds__(256) void finalize_kernel(
    const float* __restrict__ rowsum, const float* __restrict__ colsum,
    const float* __restrict__ diag, float* __restrict__ out)
{
    float s = 0.f;
    for (int i = threadIdx.x; i < 3 * NB; i += 256) {
        s += 0.5f * (logf(rowsum[i]) + logf(colsum[i])) + 10.0f - 10.0f * diag[i];
    }
    #pragma unroll
    for (int m = 32; m >= 1; m >>= 1) s += __shfl_xor(s, m);
    __shared__ float sw[4];
    if ((threadIdx.x & 63) == 0) sw[threadIdx.x >> 6] = s;
    __syncthreads();
    if (threadIdx.x == 0)
        out[0] = (sw[0] + sw[1] + sw[2] + sw[3]) * (1.0f / (3.0f * NB));
}

extern "C" void kernel_launch(void* const* d_in, const int* in_sizes, int n_in,
                              void* d_out, int out_size, void* d_ws, size_t ws_size,
                              hipStream_t stream) {
    const float* z0 = (const float*)d_in[0];
    const float* z1 = (const float*)d_in[1];
    const float* z2 = (const float*)d_in[2];
    float* out = (float*)d_out;

    char* ws = (char*)d_ws;
    unsigned short* nrm = (unsigned short*)ws;              // 3*4096*512 bf16 = 12.58 MB
    const size_t nrm_bytes = (size_t)3 * NB * ND * 2;
    float* rowsum = (float*)(ws + nrm_bytes);               // 3*4096 f32
    float* colsum = rowsum + 3 * NB;                        // 3*4096 f32
    float* diag = colsum + 3 * NB;                          // 3*4096 f32

    hipMemsetAsync(rowsum, 0, (size_t)2 * 3 * NB * sizeof(float), stream);
    nrm_kernel<<<dim3(NB, 3), 128, 0, stream>>>(z0, z1, z2, nrm);
    diag_kernel<<<(3 * NB * 64) / 256, 256, 0, stream>>>(nrm, diag);
    pair_gemm_kernel<<<dim3(NB / 128, NB / 128, 3), 256, 0, stream>>>(nrm, rowsum, colsum);
    finalize_kernel<<<1, 256, 0, stream>>>(rowsum, colsum, diag, out);
}

// Round 2
// 121.465 us; speedup vs baseline: 1.1623x; 1.1623x over previous
//
#include <hip/hip_runtime.h>
#include <hip/hip_bf16.h>

#define NB 4096
#define ND 512

typedef short bf16x8 __attribute__((ext_vector_type(8)));
typedef float f32x4 __attribute__((ext_vector_type(4)));

__device__ __forceinline__ float bf2f(unsigned short u) {
    return __uint_as_float(((unsigned int)u) << 16);
}

__device__ __forceinline__ unsigned short f2bf(float f) {
    unsigned int u = __float_as_uint(f);
    unsigned int r = (u + 0x7FFFu + ((u >> 16) & 1u)) >> 16;
    return (unsigned short)r;
}

// ---------------- normalize + cast to bf16 ----------------
__global__ __launch_bounds__(128) void nrm_kernel(
    const float* __restrict__ z0, const float* __restrict__ z1,
    const float* __restrict__ z2, unsigned short* __restrict__ nrm)
{
    const int row = blockIdx.x;
    const int p = blockIdx.y;
    const float* z = (p == 0) ? z0 : (p == 1) ? z1 : z2;
    const float4 v = reinterpret_cast<const float4*>(z)[row * (ND / 4) + threadIdx.x];
    float ss = v.x * v.x + v.y * v.y + v.z * v.z + v.w * v.w;
    #pragma unroll
    for (int m = 32; m >= 1; m >>= 1) ss += __shfl_xor(ss, m);
    __shared__ float sred[2];
    if ((threadIdx.x & 63) == 0) sred[threadIdx.x >> 6] = ss;
    __syncthreads();
    const float inv = 1.0f / fmaxf(sqrtf(sred[0] + sred[1]), 1e-8f);
    ushort4 o;
    o.x = f2bf(v.x * inv);
    o.y = f2bf(v.y * inv);
    o.z = f2bf(v.z * inv);
    o.w = f2bf(v.w * inv);
    unsigned short* dst = nrm + ((size_t)p * NB + row) * ND + threadIdx.x * 4;
    *reinterpret_cast<ushort4*>(dst) = o;
}

// ---------------- fused pair GEMM + exp + row/col sums + diag ----------------
// 1D grid 3072 (XCD-chunked swizzle), block 256 (4 waves, 2x2, 64x64/wave)
// BM=BN=128, BK=32, 3-buffer LDS pipeline (2-deep prefetch, counted vmcnt).
__global__ __launch_bounds__(256, 3) void pair_gemm_kernel(
    const unsigned short* __restrict__ nrm,
    float* __restrict__ rowsum, float* __restrict__ colsum,
    float* __restrict__ diag)
{
    // XCD-aware bijective swizzle: 3072 blocks, 8 XCDs, 384/XCD
    const int bid = blockIdx.x;
    const int swz = (bid & 7) * 384 + (bid >> 3);
    const int p = swz >> 10;
    const int rem = swz & 1023;
    const int by = rem >> 5, bx = rem & 31;
    const int ia = (p == 2) ? 1 : 0;
    const int ib = (p == 0) ? 1 : 2;

    const char* Abase = (const char*)nrm + ((size_t)ia * NB + (size_t)by * 128) * (ND * 2);
    const char* Bbase = (const char*)nrm + ((size_t)ib * NB + (size_t)bx * 128) * (ND * 2);

    __shared__ char lds[6 * 8192];  // A0 A1 A2 | B0 B1 B2 (8 KB tiles: 128 x 32 bf16)

    const int tid = threadIdx.x;
    const int lane = tid & 63;
    const int w = tid >> 6;
    const int wr = w >> 1, wc = w & 1;
    const int lr = lane & 15, lg = lane >> 4;

    // Staging: 512 chunks of 16B per tile, LDS linear (global_load_lds rule).
    // Row r = c>>2 (64B rows), phys slot qp = c&3 holds logical slot qp^s(r),
    // s(r) = (r ^ (r>>2)) & 3  -> inverse-swizzled SOURCE address (rule 21).
    int srcOff[2], ldsOff[2];
    #pragma unroll
    for (int s2 = 0; s2 < 2; ++s2) {
        const int c = (w * 2 + s2) * 64 + lane;
        const int r = c >> 2, qp = c & 3;
        const int ql = qp ^ ((r ^ (r >> 2)) & 3);
        srcOff[s2] = r * (ND * 2) + ql * 16;
        ldsOff[s2] = (w * 2 + s2) * 1024;  // wave-uniform LDS base per instr
    }

    // ds_read offsets: logical (row R, slot lg) -> phys slot lg ^ s(R);
    // since R = (mult of 16) + lr, s(R) = (lr ^ (lr>>2)) & 3 for all m.
    const int slotB = (lg ^ ((lr ^ (lr >> 2)) & 3)) * 16;
    int aoff[4], boff[4];
    #pragma unroll
    for (int m = 0; m < 4; ++m) {
        aoff[m] = (wr * 64 + m * 16 + lr) * 64 + slotB;
        boff[m] = (wc * 64 + m * 16 + lr) * 64 + slotB + 3 * 8192;
    }

    f32x4 acc[4][4] = {};

    #define STAGE(bufi, kb) do {                                                      \
        _Pragma("unroll")                                                             \
        for (int s2 = 0; s2 < 2; ++s2) {                                              \
            __builtin_amdgcn_global_load_lds(                                         \
                (const __attribute__((address_space(1))) void*)(Abase + srcOff[s2] + (kb)), \
                (__attribute__((address_space(3))) void*)(lds + (bufi) * 8192 + ldsOff[s2]), \
                16, 0, 0);                                                            \
            __builtin_amdgcn_global_load_lds(                                         \
                (const __attribute__((address_space(1))) void*)(Bbase + srcOff[s2] + (kb)), \
                (__attribute__((address_space(3))) void*)(lds + 3 * 8192 + (bufi) * 8192 + ldsOff[s2]), \
                16, 0, 0);                                                            \
        }                                                                             \
    } while (0)

    // prologue: tiles 0 and 1 in flight (8 loads/wave)
    STAGE(0, 0);
    STAGE(1, 64);

    int cur = 0, stg = 2;
    constexpr int NT = ND / 32;  // 16
    for (int t = 0; t < NT; ++t) {
        if (t < NT - 2) STAGE(stg, (t + 2) * 64);
        // counted vmcnt: keep tiles t+1, t+2 (4 loads each) in flight
        if (t < NT - 2)       asm volatile("s_waitcnt vmcnt(8)" ::: "memory");
        else if (t == NT - 2) asm volatile("s_waitcnt vmcnt(4)" ::: "memory");
        else                  asm volatile("s_waitcnt vmcnt(0)" ::: "memory");
        __builtin_amdgcn_s_barrier();
        asm volatile("" ::: "memory");  // keep ds_reads below the barrier

        const char* bufp = lds + cur * 8192;
        bf16x8 af[4], bf[4];
        #pragma unroll
        for (int m = 0; m < 4; ++m) af[m] = *(const bf16x8*)(bufp + aoff[m]);
        #pragma unroll
        for (int n = 0; n < 4; ++n) bf[n] = *(const bf16x8*)(bufp + boff[n]);
        #pragma unroll
        for (int m = 0; m < 4; ++m)
            #pragma unroll
            for (int n = 0; n < 4; ++n)
                acc[m][n] = __builtin_amdgcn_mfma_f32_16x16x32_bf16(af[m], bf[n], acc[m][n], 0, 0, 0);

        asm volatile("" ::: "memory");  // keep ds_reads above the closing barrier
        __builtin_amdgcn_s_barrier();   // buf[cur] free to overwrite next iter
        cur = (cur == 2) ? 0 : cur + 1;
        stg = (stg == 2) ? 0 : stg + 1;
    }
    #undef STAGE

    // ---- diag extraction (pre-exp): global row == global col ----
    // C frag: col = lr, row = lg*4 + j  =>  diagonal lanes have lr>>2 == lg.
    if (bx == by && wr == wc) {
        #pragma unroll
        for (int m = 0; m < 4; ++m)
            #pragma unroll
            for (int j = 0; j < 4; ++j)
                if (lr == lg * 4 + j)
                    diag[p * NB + by * 128 + wr * 64 + m * 16 + lr] = acc[m][m][j];
    }

    // ---- epilogue: e = exp2(sim*10*log2e - 10*log2e), row/col partials ----
    constexpr float C10 = 14.42695040888963f;
    float rs[4][4];
    float cs[4] = {0.f, 0.f, 0.f, 0.f};
    #pragma unroll
    for (int m = 0; m < 4; ++m)
        #pragma unroll
        for (int j = 0; j < 4; ++j) rs[m][j] = 0.f;

    #pragma unroll
    for (int m = 0; m < 4; ++m)
        #pragma unroll
        for (int n = 0; n < 4; ++n)
            #pragma unroll
            for (int j = 0; j < 4; ++j) {
                float e = exp2f(fmaf(acc[m][n][j], C10, -C10));
                rs[m][j] += e;
                cs[n] += e;
            }

    #pragma unroll
    for (int m = 0; m < 4; ++m)
        #pragma unroll
        for (int j = 0; j < 4; ++j) {
            float v = rs[m][j];
            v += __shfl_xor(v, 1);
            v += __shfl_xor(v, 2);
            v += __shfl_xor(v, 4);
            v += __shfl_xor(v, 8);
            rs[m][j] = v;
        }
    #pragma unroll
    for (int n = 0; n < 4; ++n) {
        float v = cs[n];
        v += __shfl_xor(v, 16);
        v += __shfl_xor(v, 32);
        cs[n] = v;
    }

    float* rowp = rowsum + p * NB + by * 128;
    float* colp = colsum + p * NB + bx * 128;
    if (lr == 0) {
        #pragma unroll
        for (int m = 0; m < 4; ++m)
            #pragma unroll
            for (int j = 0; j < 4; ++j)
                atomicAdd(&rowp[wr * 64 + m * 16 + lg * 4 + j], rs[m][j]);
    }
    if (lg == 0) {
        #pragma unroll
        for (int n = 0; n < 4; ++n)
            atomicAdd(&colp[wc * 64 + n * 16 + lr], cs[n]);
    }
}

// ---------------- final reduce ----------------
__global__ __launch_bounds__(256) void finalize_kernel(
    const float* __restrict__ rowsum, const float* __restrict__ colsum,
    const float* __restrict__ diag, float* __restrict__ out)
{
    float s = 0.f;
    for (int i = threadIdx.x; i < 3 * NB; i += 256) {
        s += 0.5f * (logf(rowsum[i]) + logf(colsum[i])) + 10.0f - 10.0f * diag[i];
    }
    #pragma unroll
    for (int m = 32; m >= 1; m >>= 1) s += __shfl_xor(s, m);
    __shared__ float sw[4];
    if ((threadIdx.x & 63) == 0) sw[threadIdx.x >> 6] = s;
    __syncthreads();
    if (threadIdx.x == 0)
        out[0] = (sw[0] + sw[1] + sw[2] + sw[3]) * (1.0f / (3.0f * NB));
}

extern "C" void kernel_launch(void* const* d_in, const int* in_sizes, int n_in,
                              void* d_out, int out_size, void* d_ws, size_t ws_size,
                              hipStream_t stream) {
    const float* z0 = (const float*)d_in[0];
    const float* z1 = (const float*)d_in[1];
    const float* z2 = (const float*)d_in[2];
    float* out = (float*)d_out;

    char* ws = (char*)d_ws;
    unsigned short* nrm = (unsigned short*)ws;              // 3*4096*512 bf16
    const size_t nrm_bytes = (size_t)3 * NB * ND * 2;
    float* rowsum = (float*)(ws + nrm_bytes);               // 3*4096 f32
    float* colsum = rowsum + 3 * NB;                        // 3*4096 f32
    float* diag = colsum + 3 * NB;                          // 3*4096 f32 (fully overwritten)

    hipMemsetAsync(rowsum, 0, (size_t)2 * 3 * NB * sizeof(float), stream);
    nrm_kernel<<<dim3(NB, 3), 128, 0, stream>>>(z0, z1, z2, nrm);
    pair_gemm_kernel<<<3072, 256, 0, stream>>>(nrm, rowsum, colsum, diag);
    finalize_kernel<<<1, 256, 0, stream>>>(rowsum, colsum, diag, out);
}

// Round 3
// 114.725 us; speedup vs baseline: 1.2305x; 1.0587x over previous
//
#include <hip/hip_runtime.h>
#include <hip/hip_bf16.h>

#define NB 4096
#define ND 512

typedef short bf16x8 __attribute__((ext_vector_type(8)));
typedef float f32x4 __attribute__((ext_vector_type(4)));

__device__ __forceinline__ unsigned short f2bf(float f) {
    unsigned int u = __float_as_uint(f);
    unsigned int r = (u + 0x7FFFu + ((u >> 16) & 1u)) >> 16;
    return (unsigned short)r;
}

// ---------------- normalize + cast to bf16 (wave per row) ----------------
__global__ __launch_bounds__(256) void nrm_kernel(
    const float* __restrict__ z0, const float* __restrict__ z1,
    const float* __restrict__ z2, unsigned short* __restrict__ nrm)
{
    const int w = threadIdx.x >> 6, lane = threadIdx.x & 63;
    const int row = blockIdx.x * 4 + w;
    const int p = blockIdx.y;
    const float* z = (p == 0) ? z0 : (p == 1) ? z1 : z2;
    const float4* zr = (const float4*)(z + (size_t)row * ND);
    const float4 a = zr[lane * 2], b = zr[lane * 2 + 1];
    float ss = a.x * a.x + a.y * a.y + a.z * a.z + a.w * a.w
             + b.x * b.x + b.y * b.y + b.z * b.z + b.w * b.w;
    #pragma unroll
    for (int m = 32; m >= 1; m >>= 1) ss += __shfl_xor(ss, m);
    const float inv = 1.0f / fmaxf(sqrtf(ss), 1e-8f);
    uint4 o;
    o.x = f2bf(a.x * inv) | ((unsigned)f2bf(a.y * inv) << 16);
    o.y = f2bf(a.z * inv) | ((unsigned)f2bf(a.w * inv) << 16);
    o.z = f2bf(b.x * inv) | ((unsigned)f2bf(b.y * inv) << 16);
    o.w = f2bf(b.z * inv) | ((unsigned)f2bf(b.w * inv) << 16);
    *(uint4*)(nrm + ((size_t)p * NB + row) * ND + lane * 8) = o;
}

// ---------------- fused pair GEMM: 256x256 tile, 8 waves, phase-split ----------------
// BK=32, 3 LDS buffers (96 KB), counted vmcnt(4), 2 phases per K-tile.
__global__ __launch_bounds__(512, 2) void pair_gemm_kernel(
    const unsigned short* __restrict__ nrm,
    float* __restrict__ rowsum, float* __restrict__ colsum,
    float* __restrict__ diag)
{
    // XCD-chunked bijective swizzle: 768 blocks = 8 XCDs x 96
    const int bid = blockIdx.x;
    const int swz = (bid & 7) * 96 + (bid >> 3);
    const int p = swz >> 8;
    const int rem = swz & 255;
    const int by = rem >> 4, bx = rem & 15;
    const int ia = (p == 2) ? 1 : 0;
    const int ib = (p == 0) ? 1 : 2;

    const char* Abase = (const char*)nrm + ((size_t)ia * NB + (size_t)by * 256) * (ND * 2);
    const char* Bbase = (const char*)nrm + ((size_t)ib * NB + (size_t)bx * 256) * (ND * 2);

    __shared__ char lds[3 * 32768];  // buf: A[256][32] (16KB) then B[256][32] (16KB)

    const int tid = threadIdx.x;
    const int lane = tid & 63;
    const int w = tid >> 6;
    const int wr = w >> 2, wc = w & 3;   // 2M x 4N wave grid; wave tile 128x64
    const int lr = lane & 15, lg = lane >> 4;

    // Staging: per operand-tile 1024 x 16B chunks, LDS linear (c*16).
    // Source inverse-swizzled: row r, phys slot qp holds logical qp^s(r),
    // s(r) = (r ^ (r>>2)) & 3  (64B rows -> 4 slots of 16B).
    int srcOff[2], ldsOff[2];
    #pragma unroll
    for (int s2 = 0; s2 < 2; ++s2) {
        const int c = s2 * 512 + tid;
        const int r = c >> 2, qp = c & 3;
        const int ql = qp ^ ((r ^ (r >> 2)) & 3);
        srcOff[s2] = r * (ND * 2) + ql * 16;
        ldsOff[s2] = s2 * 8192 + w * 1024;  // wave-uniform dest base
    }

    // ds_read: logical slot lg at row R -> phys slot lg ^ s(R); R=16k+lr =>
    // s(R) = (lr ^ (lr>>2)) & 3.
    const int slot = (lg ^ ((lr ^ (lr >> 2)) & 3)) * 16;
    int aoff[8], boff[4];
    #pragma unroll
    for (int m = 0; m < 8; ++m) aoff[m] = (wr * 128 + m * 16 + lr) * 64 + slot;
    #pragma unroll
    for (int n = 0; n < 4; ++n) boff[n] = 16384 + (wc * 64 + n * 16 + lr) * 64 + slot;

    f32x4 acc[8][4] = {};

    #define STAGE_A(bufi, kb) do {                                                      \
        _Pragma("unroll")                                                               \
        for (int s2 = 0; s2 < 2; ++s2)                                                  \
            __builtin_amdgcn_global_load_lds(                                           \
                (const __attribute__((address_space(1))) void*)(Abase + srcOff[s2] + (kb)), \
                (__attribute__((address_space(3))) void*)(lds + (bufi) * 32768 + ldsOff[s2]), \
                16, 0, 0);                                                              \
    } while (0)
    #define STAGE_B(bufi, kb) do {                                                      \
        _Pragma("unroll")                                                               \
        for (int s2 = 0; s2 < 2; ++s2)                                                  \
            __builtin_amdgcn_global_load_lds(                                           \
                (const __attribute__((address_space(1))) void*)(Bbase + srcOff[s2] + (kb)), \
                (__attribute__((address_space(3))) void*)(lds + (bufi) * 32768 + 16384 + ldsOff[s2]), \
                16, 0, 0);                                                              \
    } while (0)

    // prologue: tiles 0,1 in flight (8 instr/thread); gate tile 0 (vmcnt(4))
    STAGE_A(0, 0); STAGE_B(0, 0);
    STAGE_A(1, 64); STAGE_B(1, 64);
    asm volatile("s_waitcnt vmcnt(4)" ::: "memory");
    __builtin_amdgcn_s_barrier();

    int cur = 0;
    #pragma unroll 1
    for (int t = 0; t < 16; ++t) {
        const int kb2 = (t + 2) * 64;
        int stg = cur + 2; if (stg >= 3) stg -= 3;
        const char* bufp = lds + cur * 32768;

        // ---------- phase 0: quadrant m=0..3 ----------
        bf16x8 af[4], bf[4];
        #pragma unroll
        for (int m = 0; m < 4; ++m) af[m] = *(const bf16x8*)(bufp + aoff[m]);
        #pragma unroll
        for (int n = 0; n < 4; ++n) bf[n] = *(const bf16x8*)(bufp + boff[n]);
        if (t < 14) STAGE_A(stg, kb2);
        __builtin_amdgcn_s_barrier();
        asm volatile("s_waitcnt lgkmcnt(0)" ::: "memory");
        __builtin_amdgcn_sched_barrier(0);
        __builtin_amdgcn_s_setprio(1);
        #pragma unroll
        for (int m = 0; m < 4; ++m)
            #pragma unroll
            for (int n = 0; n < 4; ++n)
                acc[m][n] = __builtin_amdgcn_mfma_f32_16x16x32_bf16(af[m], bf[n], acc[m][n], 0, 0, 0);
        __builtin_amdgcn_s_setprio(0);
        __builtin_amdgcn_s_barrier();

        // ---------- phase 1: quadrant m=4..7 ----------
        bf16x8 ag[4];
        #pragma unroll
        for (int m = 0; m < 4; ++m) ag[m] = *(const bf16x8*)(bufp + aoff[m + 4]);
        if (t < 14) STAGE_B(stg, kb2);
        // gate: tile t+1 landed (allow tile t+2's 4 loads in flight)
        if (t < 14)       asm volatile("s_waitcnt vmcnt(4)" ::: "memory");
        else if (t == 14) asm volatile("s_waitcnt vmcnt(0)" ::: "memory");
        __builtin_amdgcn_s_barrier();
        asm volatile("s_waitcnt lgkmcnt(0)" ::: "memory");
        __builtin_amdgcn_sched_barrier(0);
        __builtin_amdgcn_s_setprio(1);
        #pragma unroll
        for (int m = 0; m < 4; ++m)
            #pragma unroll
            for (int n = 0; n < 4; ++n)
                acc[m + 4][n] = __builtin_amdgcn_mfma_f32_16x16x32_bf16(ag[m], bf[n], acc[m + 4][n], 0, 0, 0);
        __builtin_amdgcn_s_setprio(0);
        __builtin_amdgcn_s_barrier();

        cur += 1; if (cur >= 3) cur = 0;
    }
    #undef STAGE_A
    #undef STAGE_B

    // ---- diag (pre-exp): C frag row = lg*4+j, col = lr ----
    if (bx == by) {
        #pragma unroll
        for (int m = 0; m < 8; ++m)
            #pragma unroll
            for (int n = 0; n < 4; ++n)
                #pragma unroll
                for (int j = 0; j < 4; ++j) {
                    const int r = wr * 128 + m * 16 + lg * 4 + j;
                    const int c = wc * 64 + n * 16 + lr;
                    if (r == c) diag[p * NB + by * 256 + r] = acc[m][n][j];
                }
    }

    // ---- epilogue: e = exp2(sim*10*log2e - 10*log2e), row/col partials ----
    constexpr float C10 = 14.42695040888963f;
    float rs[8][4];
    float cs[4] = {0.f, 0.f, 0.f, 0.f};
    #pragma unroll
    for (int m = 0; m < 8; ++m)
        #pragma unroll
        for (int j = 0; j < 4; ++j) rs[m][j] = 0.f;

    #pragma unroll
    for (int m = 0; m < 8; ++m)
        #pragma unroll
        for (int n = 0; n < 4; ++n)
            #pragma unroll
            for (int j = 0; j < 4; ++j) {
                float e = exp2f(fmaf(acc[m][n][j], C10, -C10));
                rs[m][j] += e;
                cs[n] += e;
            }

    #pragma unroll
    for (int m = 0; m < 8; ++m)
        #pragma unroll
        for (int j = 0; j < 4; ++j) {
            float v = rs[m][j];
            v += __shfl_xor(v, 1);
            v += __shfl_xor(v, 2);
            v += __shfl_xor(v, 4);
            v += __shfl_xor(v, 8);
            rs[m][j] = v;
        }
    #pragma unroll
    for (int n = 0; n < 4; ++n) {
        float v = cs[n];
        v += __shfl_xor(v, 16);
        v += __shfl_xor(v, 32);
        cs[n] = v;
    }

    float* rowp = rowsum + p * NB + by * 256 + wr * 128;
    float* colp = colsum + p * NB + bx * 256 + wc * 64;
    if (lr == 0) {
        #pragma unroll
        for (int m = 0; m < 8; ++m)
            #pragma unroll
            for (int j = 0; j < 4; ++j)
                atomicAdd(&rowp[m * 16 + lg * 4 + j], rs[m][j]);
    }
    if (lg == 0) {
        #pragma unroll
        for (int n = 0; n < 4; ++n)
            atomicAdd(&colp[n * 16 + lr], cs[n]);
    }
}

// ---------------- final reduce ----------------
__global__ __launch_bounds__(1024) void finalize_kernel(
    const float* __restrict__ rowsum, const float* __restrict__ colsum,
    const float* __restrict__ diag, float* __restrict__ out)
{
    float s = 0.f;
    for (int i = threadIdx.x; i < 3 * NB; i += 1024) {
        s += 0.5f * (logf(rowsum[i]) + logf(colsum[i])) + 10.0f - 10.0f * diag[i];
    }
    #pragma unroll
    for (int m = 32; m >= 1; m >>= 1) s += __shfl_xor(s, m);
    __shared__ float sw[16];
    if ((threadIdx.x & 63) == 0) sw[threadIdx.x >> 6] = s;
    __syncthreads();
    if (threadIdx.x == 0) {
        float t = 0.f;
        #pragma unroll
        for (int i = 0; i < 16; ++i) t += sw[i];
        out[0] = t * (1.0f / (3.0f * NB));
    }
}

extern "C" void kernel_launch(void* const* d_in, const int* in_sizes, int n_in,
                              void* d_out, int out_size, void* d_ws, size_t ws_size,
                              hipStream_t stream) {
    const float* z0 = (const float*)d_in[0];
    const float* z1 = (const float*)d_in[1];
    const float* z2 = (const float*)d_in[2];
    float* out = (float*)d_out;

    char* ws = (char*)d_ws;
    unsigned short* nrm = (unsigned short*)ws;              // 3*4096*512 bf16
    const size_t nrm_bytes = (size_t)3 * NB * ND * 2;
    float* rowsum = (float*)(ws + nrm_bytes);               // 3*4096 f32
    float* colsum = rowsum + 3 * NB;                        // 3*4096 f32
    float* diag = colsum + 3 * NB;                          // 3*4096 f32 (fully overwritten)

    hipMemsetAsync(rowsum, 0, (size_t)2 * 3 * NB * sizeof(float), stream);
    nrm_kernel<<<dim3(NB / 4, 3), 256, 0, stream>>>(z0, z1, z2, nrm);
    pair_gemm_kernel<<<768, 512, 0, stream>>>(nrm, rowsum, colsum, diag);
    finalize_kernel<<<1, 1024, 0, stream>>>(rowsum, colsum, diag, out);
}

// Round 4
// 101.182 us; speedup vs baseline: 1.3953x; 1.1339x over previous
//
#include <hip/hip_runtime.h>
#include <hip/hip_bf16.h>

#define NB 4096
#define ND 512

typedef short bf16x8 __attribute__((ext_vector_type(8)));
typedef float f32x4 __attribute__((ext_vector_type(4)));

#define AS1 __attribute__((address_space(1)))
#define AS3 __attribute__((address_space(3)))

__device__ __forceinline__ unsigned short f2bf(float f) {
    unsigned int u = __float_as_uint(f);
    unsigned int r = (u + 0x7FFFu + ((u >> 16) & 1u)) >> 16;
    return (unsigned short)r;
}

// ---------------- normalize + cast to bf16 (wave per row) + zero-init sums ----------------
__global__ __launch_bounds__(256) void nrm_kernel(
    const float* __restrict__ z0, const float* __restrict__ z1,
    const float* __restrict__ z2, unsigned short* __restrict__ nrm,
    float* __restrict__ rowsum, float* __restrict__ colsum)
{
    const int w = threadIdx.x >> 6, lane = threadIdx.x & 63;
    const int row = blockIdx.x * 4 + w;
    const int p = blockIdx.y;
    if (lane == 0) {            // zero row/col sums (replaces memset dispatch)
        rowsum[p * NB + row] = 0.f;
        colsum[p * NB + row] = 0.f;
    }
    const float* z = (p == 0) ? z0 : (p == 1) ? z1 : z2;
    const float4* zr = (const float4*)(z + (size_t)row * ND);
    const float4 a = zr[lane * 2], b = zr[lane * 2 + 1];
    float ss = a.x * a.x + a.y * a.y + a.z * a.z + a.w * a.w
             + b.x * b.x + b.y * b.y + b.z * b.z + b.w * b.w;
    #pragma unroll
    for (int m = 32; m >= 1; m >>= 1) ss += __shfl_xor(ss, m);
    const float inv = 1.0f / fmaxf(sqrtf(ss), 1e-8f);
    uint4 o;
    o.x = f2bf(a.x * inv) | ((unsigned)f2bf(a.y * inv) << 16);
    o.y = f2bf(a.z * inv) | ((unsigned)f2bf(a.w * inv) << 16);
    o.z = f2bf(b.x * inv) | ((unsigned)f2bf(b.y * inv) << 16);
    o.w = f2bf(b.z * inv) | ((unsigned)f2bf(b.w * inv) << 16);
    *(uint4*)(nrm + ((size_t)p * NB + row) * ND + lane * 8) = o;
}

// ---------------- fused pair GEMM: 256x256, BK=64, 8 waves, 4 phases/K-tile ----------------
// LDS: A x3 buffers (96 KB) + B x2 buffers (64 KB) = 160 KB.
// Stage during tile t: B(t+1) @ph0-1, A(t+2) @ph2-3; gate vmcnt(4) once per tile.
__global__ __launch_bounds__(512, 2) void pair_gemm_kernel(
    const unsigned short* __restrict__ nrm,
    float* __restrict__ rowsum, float* __restrict__ colsum,
    float* __restrict__ diag)
{
    // XCD-chunked bijective swizzle: 768 blocks = 8 XCDs x 96
    const int bid = blockIdx.x;
    const int swz = (bid & 7) * 96 + (bid >> 3);
    const int p = swz >> 8;
    const int rem = swz & 255;
    const int by = rem >> 4, bx = rem & 15;
    const int ia = (p == 2) ? 1 : 0;
    const int ib = (p == 0) ? 1 : 2;

    const char* Aglob = (const char*)nrm + ((size_t)ia * NB + (size_t)by * 256) * (ND * 2);
    const char* Bglob = (const char*)nrm + ((size_t)ib * NB + (size_t)bx * 256) * (ND * 2);

    __shared__ char lds[163840];  // A: [0,98304) 3x32KB ; B: [98304,163840) 2x32KB

    const int tid = threadIdx.x;
    const int lane = tid & 63;
    const int w = tid >> 6;
    const int wr = w >> 2, wc = w & 3;   // 2M x 4N; wave tile 128x64
    const int lr = lane & 15, lg = lane >> 4;

    // ---- staging chunk map (per thread 2 loads per half-tile) ----
    // half = 128 rows x 64 cols = 1024 chunks of 16B. chunk c -> LDS byte c*16
    // (linear, forced by global_load_lds). Row r=c>>3, phys slot qp=c&7 holds
    // logical slot ql = qp ^ (r&7)  -> inverse-swizzled SOURCE (rule 21).
    const int c0 = tid, c1 = tid + 512;
    const int so0 = (c0 >> 3) * 1024 + (((c0 & 7) ^ ((c0 >> 3) & 7)) * 16);
    const int so1 = (c1 >> 3) * 1024 + (((c1 & 7) ^ ((c1 >> 3) & 7)) * 16);

    // ---- ds_read offsets ----
    // k-slot kk, lane (lg,lr): logical slot = kk*4+lg, phys = (kk*4+lg)^(lr&7).
    const int sw0 = ((lg ^ (lr & 7)) * 16);            // k0
    const int sw1 = (((4 + lg) ^ (lr & 7)) * 16);      // k1
    const int aoff0 = (wr * 128 + lr) * 128 + sw0;
    const int aoff1 = (wr * 128 + lr) * 128 + sw1;
    const int boff0 = (wc * 64 + lr) * 128 + sw0;
    const int boff1 = (wc * 64 + lr) * 128 + sw1;

    f32x4 acc[8][4] = {};

    #define STAGE(glob, h, tt, dstbase) do {                                              \
        __builtin_amdgcn_global_load_lds(                                                 \
            (const AS1 void*)((glob) + (h) * 131072 + so0 + (tt) * 128),                  \
            (AS3 void*)(lds + (dstbase) + (h) * 16384 + c0 * 16), 16, 0, 0);              \
        __builtin_amdgcn_global_load_lds(                                                 \
            (const AS1 void*)((glob) + (h) * 131072 + so1 + (tt) * 128),                  \
            (AS3 void*)(lds + (dstbase) + (h) * 16384 + c1 * 16), 16, 0, 0);              \
    } while (0)

    // prologue: A(0)->abuf0, B(0)->bbuf0, A(1)->abuf1 ; keep A(1) in flight
    STAGE(Aglob, 0, 0, 0);      STAGE(Aglob, 1, 0, 0);
    STAGE(Bglob, 0, 0, 98304);  STAGE(Bglob, 1, 0, 98304);
    STAGE(Aglob, 0, 1, 32768);  STAGE(Aglob, 1, 1, 32768);
    asm volatile("s_waitcnt vmcnt(4)" ::: "memory");
    __builtin_amdgcn_s_barrier();

    int ab = 0;  // (t%3)*32768
    #pragma unroll 1
    for (int t = 0; t < 8; ++t) {
        int abn = ab + 32768; if (abn >= 98304) abn -= 98304;
        int ab2 = abn + 32768; if (ab2 >= 98304) ab2 -= 98304;
        const char* abuf = lds + ab;
        const char* bbuf = lds + 98304 + (t & 1) * 32768;
        const int bbn = 98304 + ((t + 1) & 1) * 32768;

        bf16x8 af[4], bf[4];

        // ---------- phase 0: k0, m0-3 ----------
        #pragma unroll
        for (int m = 0; m < 4; ++m) af[m] = *(const bf16x8*)(abuf + aoff0 + m * 2048);
        #pragma unroll
        for (int n = 0; n < 4; ++n) bf[n] = *(const bf16x8*)(bbuf + boff0 + n * 2048);
        if (t < 7) STAGE(Bglob, 0, t + 1, bbn);
        __builtin_amdgcn_s_barrier();
        asm volatile("s_waitcnt lgkmcnt(0)" ::: "memory");
        __builtin_amdgcn_sched_barrier(0);
        __builtin_amdgcn_s_setprio(1);
        #pragma unroll
        for (int m = 0; m < 4; ++m)
            #pragma unroll
            for (int n = 0; n < 4; ++n)
                acc[m][n] = __builtin_amdgcn_mfma_f32_16x16x32_bf16(af[m], bf[n], acc[m][n], 0, 0, 0);
        __builtin_amdgcn_s_setprio(0);
        __builtin_amdgcn_s_barrier();

        // ---------- phase 1: k0, m4-7 ----------
        #pragma unroll
        for (int m = 0; m < 4; ++m) af[m] = *(const bf16x8*)(abuf + aoff0 + (m + 4) * 2048);
        if (t < 7) STAGE(Bglob, 1, t + 1, bbn);
        __builtin_amdgcn_s_barrier();
        asm volatile("s_waitcnt lgkmcnt(0)" ::: "memory");
        __builtin_amdgcn_sched_barrier(0);
        __builtin_amdgcn_s_setprio(1);
        #pragma unroll
        for (int m = 0; m < 4; ++m)
            #pragma unroll
            for (int n = 0; n < 4; ++n)
                acc[m + 4][n] = __builtin_amdgcn_mfma_f32_16x16x32_bf16(af[m], bf[n], acc[m + 4][n], 0, 0, 0);
        __builtin_amdgcn_s_setprio(0);
        __builtin_amdgcn_s_barrier();

        // ---------- phase 2: k1, m0-3 ----------
        #pragma unroll
        for (int m = 0; m < 4; ++m) af[m] = *(const bf16x8*)(abuf + aoff1 + m * 2048);
        #pragma unroll
        for (int n = 0; n < 4; ++n) bf[n] = *(const bf16x8*)(bbuf + boff1 + n * 2048);
        if (t < 6) STAGE(Aglob, 0, t + 2, ab2);
        __builtin_amdgcn_s_barrier();
        asm volatile("s_waitcnt lgkmcnt(0)" ::: "memory");
        __builtin_amdgcn_sched_barrier(0);
        __builtin_amdgcn_s_setprio(1);
        #pragma unroll
        for (int m = 0; m < 4; ++m)
            #pragma unroll
            for (int n = 0; n < 4; ++n)
                acc[m][n] = __builtin_amdgcn_mfma_f32_16x16x32_bf16(af[m], bf[n], acc[m][n], 0, 0, 0);
        __builtin_amdgcn_s_setprio(0);
        __builtin_amdgcn_s_barrier();

        // ---------- phase 3: k1, m4-7 (+ per-tile gate) ----------
        #pragma unroll
        for (int m = 0; m < 4; ++m) af[m] = *(const bf16x8*)(abuf + aoff1 + (m + 4) * 2048);
        if (t < 6) STAGE(Aglob, 1, t + 2, ab2);
        __builtin_amdgcn_s_barrier();
        asm volatile("s_waitcnt lgkmcnt(0)" ::: "memory");
        __builtin_amdgcn_sched_barrier(0);
        __builtin_amdgcn_s_setprio(1);
        #pragma unroll
        for (int m = 0; m < 4; ++m)
            #pragma unroll
            for (int n = 0; n < 4; ++n)
                acc[m + 4][n] = __builtin_amdgcn_mfma_f32_16x16x32_bf16(af[m], bf[n], acc[m + 4][n], 0, 0, 0);
        __builtin_amdgcn_s_setprio(0);
        // gate: drain A(t+1)+B(t+1); leave A(t+2)'s 4 loads in flight
        if (t < 6)       asm volatile("s_waitcnt vmcnt(4)" ::: "memory");
        else if (t == 6) asm volatile("s_waitcnt vmcnt(0)" ::: "memory");
        __builtin_amdgcn_s_barrier();

        ab = abn;
    }
    #undef STAGE

    // ---- diag (pre-exp): C frag row = lg*4+j (within 16), col = lr ----
    if (bx == by) {
        #pragma unroll
        for (int m = 0; m < 8; ++m)
            #pragma unroll
            for (int n = 0; n < 4; ++n)
                #pragma unroll
                for (int j = 0; j < 4; ++j) {
                    const int r = wr * 128 + m * 16 + lg * 4 + j;
                    const int c = wc * 64 + n * 16 + lr;
                    if (r == c) diag[p * NB + by * 256 + r] = acc[m][n][j];
                }
    }

    // ---- epilogue: e = exp2(sim*10*log2e - 10*log2e), row/col partials ----
    constexpr float C10 = 14.42695040888963f;
    float rs[8][4];
    float cs[4] = {0.f, 0.f, 0.f, 0.f};
    #pragma unroll
    for (int m = 0; m < 8; ++m)
        #pragma unroll
        for (int j = 0; j < 4; ++j) rs[m][j] = 0.f;

    #pragma unroll
    for (int m = 0; m < 8; ++m)
        #pragma unroll
        for (int n = 0; n < 4; ++n)
            #pragma unroll
            for (int j = 0; j < 4; ++j) {
                float e = exp2f(fmaf(acc[m][n][j], C10, -C10));
                rs[m][j] += e;
                cs[n] += e;
            }

    #pragma unroll
    for (int m = 0; m < 8; ++m)
        #pragma unroll
        for (int j = 0; j < 4; ++j) {
            float v = rs[m][j];
            v += __shfl_xor(v, 1);
            v += __shfl_xor(v, 2);
            v += __shfl_xor(v, 4);
            v += __shfl_xor(v, 8);
            rs[m][j] = v;
        }
    #pragma unroll
    for (int n = 0; n < 4; ++n) {
        float v = cs[n];
        v += __shfl_xor(v, 16);
        v += __shfl_xor(v, 32);
        cs[n] = v;
    }

    float* rowp = rowsum + p * NB + by * 256 + wr * 128;
    float* colp = colsum + p * NB + bx * 256 + wc * 64;
    if (lr == 0) {
        #pragma unroll
        for (int m = 0; m < 8; ++m)
            #pragma unroll
            for (int j = 0; j < 4; ++j)
                atomicAdd(&rowp[m * 16 + lg * 4 + j], rs[m][j]);
    }
    if (lg == 0) {
        #pragma unroll
        for (int n = 0; n < 4; ++n)
            atomicAdd(&colp[n * 16 + lr], cs[n]);
    }
}

// ---------------- final reduce ----------------
__global__ __launch_bounds__(1024) void finalize_kernel(
    const float* __restrict__ rowsum, const float* __restrict__ colsum,
    const float* __restrict__ diag, float* __restrict__ out)
{
    float s = 0.f;
    for (int i = threadIdx.x; i < 3 * NB; i += 1024) {
        s += 0.5f * (logf(rowsum[i]) + logf(colsum[i])) + 10.0f - 10.0f * diag[i];
    }
    #pragma unroll
    for (int m = 32; m >= 1; m >>= 1) s += __shfl_xor(s, m);
    __shared__ float sw[16];
    if ((threadIdx.x & 63) == 0) sw[threadIdx.x >> 6] = s;
    __syncthreads();
    if (threadIdx.x == 0) {
        float t = 0.f;
        #pragma unroll
        for (int i = 0; i < 16; ++i) t += sw[i];
        out[0] = t * (1.0f / (3.0f * NB));
    }
}

extern "C" void kernel_launch(void* const* d_in, const int* in_sizes, int n_in,
                              void* d_out, int out_size, void* d_ws, size_t ws_size,
                              hipStream_t stream) {
    const float* z0 = (const float*)d_in[0];
    const float* z1 = (const float*)d_in[1];
    const float* z2 = (const float*)d_in[2];
    float* out = (float*)d_out;

    char* ws = (char*)d_ws;
    unsigned short* nrm = (unsigned short*)ws;              // 3*4096*512 bf16
    const size_t nrm_bytes = (size_t)3 * NB * ND * 2;
    float* rowsum = (float*)(ws + nrm_bytes);               // 3*4096 f32
    float* colsum = rowsum + 3 * NB;                        // 3*4096 f32
    float* diag = colsum + 3 * NB;                          // 3*4096 f32 (fully overwritten)

    nrm_kernel<<<dim3(NB / 4, 3), 256, 0, stream>>>(z0, z1, z2, nrm, rowsum, colsum);
    pair_gemm_kernel<<<768, 512, 0, stream>>>(nrm, rowsum, colsum, diag);
    finalize_kernel<<<1, 1024, 0, stream>>>(rowsum, colsum, diag, out);
}

// Round 5
// 94.581 us; speedup vs baseline: 1.4926x; 1.0698x over previous
//
#include <hip/hip_runtime.h>
#include <hip/hip_bf16.h>

#define NB 4096
#define ND 512

typedef short bf16x8 __attribute__((ext_vector_type(8)));
typedef float f32x4 __attribute__((ext_vector_type(4)));

#define AS1 __attribute__((address_space(1)))
#define AS3 __attribute__((address_space(3)))

__device__ __forceinline__ unsigned short f2bf(float f) {
    unsigned int u = __float_as_uint(f);
    unsigned int r = (u + 0x7FFFu + ((u >> 16) & 1u)) >> 16;
    return (unsigned short)r;
}

// ---------------- normalize + cast to bf16 (wave per row) + zero-init sums ----------------
__global__ __launch_bounds__(256) void nrm_kernel(
    const float* __restrict__ z0, const float* __restrict__ z1,
    const float* __restrict__ z2, unsigned short* __restrict__ nrm,
    float* __restrict__ rowsum, float* __restrict__ colsum)
{
    const int w = threadIdx.x >> 6, lane = threadIdx.x & 63;
    const int row = blockIdx.x * 4 + w;
    const int p = blockIdx.y;
    if (lane == 0) {
        rowsum[p * NB + row] = 0.f;
        colsum[p * NB + row] = 0.f;
    }
    const float* z = (p == 0) ? z0 : (p == 1) ? z1 : z2;
    const float4* zr = (const float4*)(z + (size_t)row * ND);
    const float4 a = zr[lane * 2], b = zr[lane * 2 + 1];
    float ss = a.x * a.x + a.y * a.y + a.z * a.z + a.w * a.w
             + b.x * b.x + b.y * b.y + b.z * b.z + b.w * b.w;
    #pragma unroll
    for (int m = 32; m >= 1; m >>= 1) ss += __shfl_xor(ss, m);
    const float inv = 1.0f / fmaxf(sqrtf(ss), 1e-8f);
    uint4 o;
    o.x = f2bf(a.x * inv) | ((unsigned)f2bf(a.y * inv) << 16);
    o.y = f2bf(a.z * inv) | ((unsigned)f2bf(a.w * inv) << 16);
    o.z = f2bf(b.x * inv) | ((unsigned)f2bf(b.y * inv) << 16);
    o.w = f2bf(b.z * inv) | ((unsigned)f2bf(b.w * inv) << 16);
    *(uint4*)(nrm + ((size_t)p * NB + row) * ND + lane * 8) = o;
}

// ---------------- fused pair GEMM: 256x256, BK=64, 8 waves ----------------
// Software-pipelined (reads one phase ahead, compiler-counted lgkm), ONE
// barrier per K-tile. LDS: A x3 (96 KB) + B x2 (64 KB) = 160 KB.
// XCD chunking: per pair, each XCD owns an 8by x 4bx chunk (WS 3 MB < 4 MB L2).
__global__ __launch_bounds__(512, 2) void pair_gemm_kernel(
    const unsigned short* __restrict__ nrm,
    float* __restrict__ rowsum, float* __restrict__ colsum,
    float* __restrict__ diag)
{
    // 768 blocks: xcd = bid&7; rank 0..95 -> p (32 each), by/bx within chunk.
    const int bid = blockIdx.x;
    const int xcd = bid & 7;
    const int rank = bid >> 3;
    const int p = rank >> 5;           // 0..2
    const int r2 = rank & 31;
    const int by = (xcd & 1) * 8 + (r2 >> 2);
    const int bx = (xcd >> 1) * 4 + (r2 & 3);
    const int ia = (p == 2) ? 1 : 0;
    const int ib = (p == 0) ? 1 : 2;

    const char* Aglob = (const char*)nrm + ((size_t)ia * NB + (size_t)by * 256) * (ND * 2);
    const char* Bglob = (const char*)nrm + ((size_t)ib * NB + (size_t)bx * 256) * (ND * 2);

    __shared__ char lds[163840];  // A: [0,98304) 3x32KB ; B: [98304,163840) 2x32KB

    const int tid = threadIdx.x;
    const int lane = tid & 63;
    const int w = tid >> 6;
    const int wr = w >> 2, wc = w & 3;   // 2M x 4N; wave tile 128x64
    const int lr = lane & 15, lg = lane >> 4;

    // staging chunk map: row r=c>>3, phys slot qp=c&7 holds logical qp^(r&7)
    // -> inverse-swizzled SOURCE, linear LDS dest (rule 21).
    const int c0 = tid, c1 = tid + 512;
    const int so0 = (c0 >> 3) * 1024 + (((c0 & 7) ^ ((c0 >> 3) & 7)) * 16);
    const int so1 = (c1 >> 3) * 1024 + (((c1 & 7) ^ ((c1 >> 3) & 7)) * 16);

    // ds_read: logical slot kk*4+lg at row 16k+lr -> phys ^(lr&7)
    const int sw0 = ((lg ^ (lr & 7)) * 16);
    const int sw1 = (((4 + lg) ^ (lr & 7)) * 16);
    const int aoff0 = (wr * 128 + lr) * 128 + sw0;
    const int aoff1 = (wr * 128 + lr) * 128 + sw1;
    const int boff0 = (wc * 64 + lr) * 128 + sw0;
    const int boff1 = (wc * 64 + lr) * 128 + sw1;

    f32x4 acc[8][4] = {};

    #define STAGE(glob, h, tt, dstbase) do {                                              \
        __builtin_amdgcn_global_load_lds(                                                 \
            (const AS1 void*)((glob) + (h) * 131072 + so0 + (tt) * 128),                  \
            (AS3 void*)(lds + (dstbase) + (h) * 16384 + c0 * 16), 16, 0, 0);              \
        __builtin_amdgcn_global_load_lds(                                                 \
            (const AS1 void*)((glob) + (h) * 131072 + so1 + (tt) * 128),                  \
            (AS3 void*)(lds + (dstbase) + (h) * 16384 + c1 * 16), 16, 0, 0);              \
    } while (0)

    #define MFMA16(base, AF, BF) do {                                                     \
        __builtin_amdgcn_s_setprio(1);                                                    \
        _Pragma("unroll")                                                                 \
        for (int m = 0; m < 4; ++m)                                                       \
            _Pragma("unroll")                                                             \
            for (int n = 0; n < 4; ++n)                                                   \
                acc[(base) + m][n] =                                                      \
                    __builtin_amdgcn_mfma_f32_16x16x32_bf16(AF[m], BF[n], acc[(base) + m][n], 0, 0, 0); \
        __builtin_amdgcn_s_setprio(0);                                                    \
    } while (0)

    // prologue: A(0), B(0), A(1) in flight; drain A(0)+B(0)
    STAGE(Aglob, 0, 0, 0);      STAGE(Aglob, 1, 0, 0);
    STAGE(Bglob, 0, 0, 98304);  STAGE(Bglob, 1, 0, 98304);
    STAGE(Aglob, 0, 1, 32768);  STAGE(Aglob, 1, 1, 32768);
    asm volatile("s_waitcnt vmcnt(4)" ::: "memory");
    asm volatile("s_barrier" ::: "memory");

    bf16x8 afA[4], afB[4], bfA[4], bfB[4];
    {
        const char* abuf = lds;
        const char* bbuf = lds + 98304;
        #pragma unroll
        for (int m = 0; m < 4; ++m) afA[m] = *(const bf16x8*)(abuf + aoff0 + m * 2048);
        #pragma unroll
        for (int n = 0; n < 4; ++n) bfA[n] = *(const bf16x8*)(bbuf + boff0 + n * 2048);
    }

    int ab = 0;
    #pragma unroll 1
    for (int t = 0; t < 8; ++t) {
        int abn = ab + 32768; if (abn >= 98304) abn -= 98304;
        int ab2 = abn + 32768; if (ab2 >= 98304) ab2 -= 98304;
        const char* abuf = lds + ab;
        const char* bbuf = lds + 98304 + (t & 1) * 32768;
        const char* abufn = lds + abn;
        const char* bbufn = lds + 98304 + ((t + 1) & 1) * 32768;
        const int bbn = 98304 + ((t + 1) & 1) * 32768;

        // ph0: read(k0,m4-7)->afB ; stage B(t+1)h0 ; MFMA(k0,m0-3)
        #pragma unroll
        for (int m = 0; m < 4; ++m) afB[m] = *(const bf16x8*)(abuf + aoff0 + (m + 4) * 2048);
        if (t < 7) STAGE(Bglob, 0, t + 1, bbn);
        MFMA16(0, afA, bfA);

        // ph1: read(k1,m0-3)->afA, bf(k1)->bfB ; stage B(t+1)h1 ; MFMA(k0,m4-7)
        #pragma unroll
        for (int m = 0; m < 4; ++m) afA[m] = *(const bf16x8*)(abuf + aoff1 + m * 2048);
        #pragma unroll
        for (int n = 0; n < 4; ++n) bfB[n] = *(const bf16x8*)(bbuf + boff1 + n * 2048);
        if (t < 7) STAGE(Bglob, 1, t + 1, bbn);
        MFMA16(4, afB, bfA);

        // ph2: read(k1,m4-7)->afB ; stage A(t+2)h0 ; MFMA(k1,m0-3)
        #pragma unroll
        for (int m = 0; m < 4; ++m) afB[m] = *(const bf16x8*)(abuf + aoff1 + (m + 4) * 2048);
        if (t < 6) STAGE(Aglob, 0, t + 2, ab2);
        MFMA16(0, afA, bfB);

        // ph3: stage A(t+2)h1 ; gate+barrier ; read R0(t+1)->afA,bfA ; MFMA(k1,m4-7)
        if (t < 6) STAGE(Aglob, 1, t + 2, ab2);
        if (t < 6)       asm volatile("s_waitcnt vmcnt(4) lgkmcnt(0)" ::: "memory");
        else if (t == 6) asm volatile("s_waitcnt vmcnt(0) lgkmcnt(0)" ::: "memory");
        if (t < 7) {
            asm volatile("s_barrier" ::: "memory");
            #pragma unroll
            for (int m = 0; m < 4; ++m) afA[m] = *(const bf16x8*)(abufn + aoff0 + m * 2048);
            #pragma unroll
            for (int n = 0; n < 4; ++n) bfA[n] = *(const bf16x8*)(bbufn + boff0 + n * 2048);
        }
        MFMA16(4, afB, bfB);

        ab = abn;
    }
    #undef STAGE
    #undef MFMA16

    // ---- diag (pre-exp): C frag row = lg*4+j (within 16), col = lr ----
    if (bx == by) {
        #pragma unroll
        for (int m = 0; m < 8; ++m)
            #pragma unroll
            for (int n = 0; n < 4; ++n)
                #pragma unroll
                for (int j = 0; j < 4; ++j) {
                    const int r = wr * 128 + m * 16 + lg * 4 + j;
                    const int c = wc * 64 + n * 16 + lr;
                    if (r == c) diag[p * NB + by * 256 + r] = acc[m][n][j];
                }
    }

    // ---- epilogue: e = exp2(sim*10*log2e - 10*log2e), row/col partials ----
    constexpr float C10 = 14.42695040888963f;
    float rs[8][4];
    float cs[4] = {0.f, 0.f, 0.f, 0.f};
    #pragma unroll
    for (int m = 0; m < 8; ++m)
        #pragma unroll
        for (int j = 0; j < 4; ++j) rs[m][j] = 0.f;

    #pragma unroll
    for (int m = 0; m < 8; ++m)
        #pragma unroll
        for (int n = 0; n < 4; ++n)
            #pragma unroll
            for (int j = 0; j < 4; ++j) {
                float e = exp2f(fmaf(acc[m][n][j], C10, -C10));
                rs[m][j] += e;
                cs[n] += e;
            }

    #pragma unroll
    for (int m = 0; m < 8; ++m)
        #pragma unroll
        for (int j = 0; j < 4; ++j) {
            float v = rs[m][j];
            v += __shfl_xor(v, 1);
            v += __shfl_xor(v, 2);
            v += __shfl_xor(v, 4);
            v += __shfl_xor(v, 8);
            rs[m][j] = v;
        }
    #pragma unroll
    for (int n = 0; n < 4; ++n) {
        float v = cs[n];
        v += __shfl_xor(v, 16);
        v += __shfl_xor(v, 32);
        cs[n] = v;
    }

    float* rowp = rowsum + p * NB + by * 256 + wr * 128;
    float* colp = colsum + p * NB + bx * 256 + wc * 64;
    if (lr == 0) {
        #pragma unroll
        for (int m = 0; m < 8; ++m)
            #pragma unroll
            for (int j = 0; j < 4; ++j)
                atomicAdd(&rowp[m * 16 + lg * 4 + j], rs[m][j]);
    }
    if (lg == 0) {
        #pragma unroll
        for (int n = 0; n < 4; ++n)
            atomicAdd(&colp[n * 16 + lr], cs[n]);
    }
}

// ---------------- final reduce ----------------
__global__ __launch_bounds__(1024) void finalize_kernel(
    const float* __restrict__ rowsum, const float* __restrict__ colsum,
    const float* __restrict__ diag, float* __restrict__ out)
{
    float s = 0.f;
    for (int i = threadIdx.x; i < 3 * NB; i += 1024) {
        s += 0.5f * (logf(rowsum[i]) + logf(colsum[i])) + 10.0f - 10.0f * diag[i];
    }
    #pragma unroll
    for (int m = 32; m >= 1; m >>= 1) s += __shfl_xor(s, m);
    __shared__ float sw[16];
    if ((threadIdx.x & 63) == 0) sw[threadIdx.x >> 6] = s;
    __syncthreads();
    if (threadIdx.x == 0) {
        float t = 0.f;
        #pragma unroll
        for (int i = 0; i < 16; ++i) t += sw[i];
        out[0] = t * (1.0f / (3.0f * NB));
    }
}

extern "C" void kernel_launch(void* const* d_in, const int* in_sizes, int n_in,
                              void* d_out, int out_size, void* d_ws, size_t ws_size,
                              hipStream_t stream) {
    const float* z0 = (const float*)d_in[0];
    const float* z1 = (const float*)d_in[1];
    const float* z2 = (const float*)d_in[2];
    float* out = (float*)d_out;

    char* ws = (char*)d_ws;
    unsigned short* nrm = (unsigned short*)ws;              // 3*4096*512 bf16
    const size_t nrm_bytes = (size_t)3 * NB * ND * 2;
    float* rowsum = (float*)(ws + nrm_bytes);               // 3*4096 f32
    float* colsum = rowsum + 3 * NB;                        // 3*4096 f32
    float* diag = colsum + 3 * NB;                          // 3*4096 f32 (fully overwritten)

    nrm_kernel<<<dim3(NB / 4, 3), 256, 0, stream>>>(z0, z1, z2, nrm, rowsum, colsum);
    pair_gemm_kernel<<<768, 512, 0, stream>>>(nrm, rowsum, colsum, diag);
    finalize_kernel<<<1, 1024, 0, stream>>>(rowsum, colsum, diag, out);
}